// Round 18
// baseline (24.541 us; speedup 1.0000x reference)
//
#include <hip/hip_runtime.h>

#define NBATCH 4
#define NPTS   4096
#define XPT    1                  // x-points per thread
#define XCHUNK (256 * XPT)        // 256
#define NXC    (NPTS / XCHUNK)    // 16
#define YCHUNK 256                // y-points per block (128 pairs)
#define NPAIR  (YCHUNK / 2)       // 128
#define NYC    (NPTS / YCHUNK)    // 16
#define BIGF   1e30f

typedef float v2f __attribute__((ext_vector_type(2)));

// Kernel 1: partial mins with packed-f32 math.
// grid = (NXC, NYC, 2*NBATCH) = (16,16,8) = 2048 blocks -> 8 blocks/CU,
// 8 waves/SIMD (hardware max TLP for latency hiding).
// LDS pair layout per y-pair j: E0=(x_a,x_b,y_a,y_b), E1=(z_a,z_b,ry_a,ry_b)
// -> inner step: 3 v_pk_fma_f32 + 1 v_min3_f32 for TWO y (2 instr/pair).
__global__ __launch_bounds__(256)
void chamfer_min_kernel(const float* __restrict__ preds,
                        const float* __restrict__ gts,
                        const int* __restrict__ mask,
                        float* __restrict__ partial,
                        float* __restrict__ out) {
    const int zc  = blockIdx.z;
    const int dir = zc >> 2;
    const int b   = zc & 3;
    const int tid = threadIdx.x;

    // zero the output scalar exactly once (kernel2 accumulates after boundary)
    if ((zc | blockIdx.x | blockIdx.y | tid) == 0) out[0] = 0.0f;

    const float* X = (dir == 0 ? preds : gts) + (size_t)b * NPTS * 3;
    const float* Y = (dir == 0 ? gts : preds) + (size_t)b * NPTS * 3;

    __shared__ float4 sp[2 * NPAIR];   // 4 KB
    const int cbase = blockIdx.y * YCHUNK;
    if (tid < NPAIR) {
        const int ja = cbase + 2 * tid;
        const int jb = ja + 1;
        const float xa = Y[ja * 3 + 0], ya = Y[ja * 3 + 1], za = Y[ja * 3 + 2];
        const float xb = Y[jb * 3 + 0], yb = Y[jb * 3 + 1], zb = Y[jb * 3 + 2];
        float ra = xa * xa + ya * ya + za * za;
        float rb = xb * xb + yb * yb + zb * zb;
        if (dir == 0) {
            if (mask[b * NPTS + ja] == 0) ra = BIGF;
            if (mask[b * NPTS + jb] == 0) rb = BIGF;
        }
        sp[2 * tid + 0] = make_float4(xa, xb, ya, yb);
        sp[2 * tid + 1] = make_float4(za, zb, ra, rb);
    }

    // this thread's single x-point; packed splats of (-2x)
    const int x = blockIdx.x * XCHUNK + tid;
    const float v0 = X[x * 3 + 0], v1 = X[x * 3 + 1], v2 = X[x * 3 + 2];
    const float rx = v0 * v0 + v1 * v1 + v2 * v2;
    const float s0 = -2.0f * v0, s1 = -2.0f * v1, s2 = -2.0f * v2;
    const v2f A0 = (v2f){s0, s0}, A1 = (v2f){s1, s1}, A2 = (v2f){s2, s2};
    float m = BIGF;

    __syncthreads();

    #pragma unroll 4
    for (int j = 0; j < NPAIR; ++j) {
        const float4 E0 = sp[2 * j + 0];   // (x_a,x_b,y_a,y_b) broadcast
        const float4 E1 = sp[2 * j + 1];   // (z_a,z_b,ra,rb)
        const v2f X2 = (v2f){E0.x, E0.y};
        const v2f Y2 = (v2f){E0.z, E0.w};
        const v2f Z2 = (v2f){E1.x, E1.y};
        const v2f R2 = (v2f){E1.z, E1.w};
        // t = R2 + A2*Z2 + A1*Y2 + A0*X2  (3 x v_pk_fma_f32)
        v2f t = __builtin_elementwise_fma(A2, Z2, R2);
        t = __builtin_elementwise_fma(A1, Y2, t);
        t = __builtin_elementwise_fma(A0, X2, t);
        m = fminf(fminf(m, t.x), t.y);     // -> v_min3_f32
    }

    partial[((size_t)zc * NYC + blockIdx.y) * NPTS + x] = rx + m;
}

// Kernel 2: per point min over NYC=16 rows. 2 threads per float4-column
// (8 rows each, shfl_xor combine) -> 64 blocks of 256.
__global__ __launch_bounds__(256)
void chamfer_reduce_kernel(const float* __restrict__ partial,
                           const int* __restrict__ mask,
                           float* __restrict__ out) {
    const int gid = blockIdx.x * blockDim.x + threadIdx.x;
    const int h   = gid & 1;            // row-half
    const int c   = gid >> 1;           // float4-column id
    const int p4  = c * 4;              // first of 4 consecutive points
    const int dir = p4 >> 14;
    const int b   = (p4 >> 12) & 3;
    const int x   = p4 & 4095;
    const int zc  = dir * NBATCH + b;

    const float4* base = (const float4*)(partial + (size_t)zc * NYC * NPTS + x)
                       + (size_t)(h * 8) * (NPTS / 4);
    float4 m4 = base[0];
    #pragma unroll
    for (int r = 1; r < 8; ++r) {
        const float4 v = base[(size_t)r * (NPTS / 4)];
        m4.x = fminf(m4.x, v.x); m4.y = fminf(m4.y, v.y);
        m4.z = fminf(m4.z, v.z); m4.w = fminf(m4.w, v.w);
    }
    // combine halves (lanes 2i, 2i+1)
    m4.x = fminf(m4.x, __shfl_xor(m4.x, 1, 64));
    m4.y = fminf(m4.y, __shfl_xor(m4.y, 1, 64));
    m4.z = fminf(m4.z, __shfl_xor(m4.z, 1, 64));
    m4.w = fminf(m4.w, __shfl_xor(m4.w, 1, 64));

    float acc = 0.0f;
    if (h == 0) {
        if (dir == 1) {
            const int4 mk = *(const int4*)(mask + b * NPTS + x);
            acc = (mk.x ? m4.x : 0.0f) + (mk.y ? m4.y : 0.0f)
                + (mk.z ? m4.z : 0.0f) + (mk.w ? m4.w : 0.0f);
        } else {
            acc = m4.x + m4.y + m4.z + m4.w;
        }
    }

    #pragma unroll
    for (int off = 32; off > 0; off >>= 1)
        acc += __shfl_down(acc, off, 64);

    __shared__ float wsum[4];
    if ((threadIdx.x & 63) == 0) wsum[threadIdx.x >> 6] = acc;
    __syncthreads();
    if (threadIdx.x == 0)
        atomicAdd(out, wsum[0] + wsum[1] + wsum[2] + wsum[3]);
}

extern "C" void kernel_launch(void* const* d_in, const int* in_sizes, int n_in,
                              void* d_out, int out_size, void* d_ws, size_t ws_size,
                              hipStream_t stream) {
    const float* preds = (const float*)d_in[0];  // [B, Npred, 3]
    const float* gts   = (const float*)d_in[1];  // [B, Ngt, 3]
    const int*   mask  = (const int*)d_in[2];    // [B, Ngt]
    float* out = (float*)d_out;

    float* partial = (float*)d_ws;  // [8][NYC][NPTS] = 2 MB

    dim3 grid(NXC, NYC, 2 * NBATCH);
    chamfer_min_kernel<<<grid, 256, 0, stream>>>(preds, gts, mask, partial, out);

    chamfer_reduce_kernel<<<2 * (2 * NBATCH * NPTS / 4) / 256, 256, 0, stream>>>(
        partial, mask, out);
}

// Round 19
// 19.723 us; speedup vs baseline: 1.2442x; 1.2442x over previous
//
#include <hip/hip_runtime.h>

#define NBATCH 4
#define NPTS   4096
#define XPT    2                  // x-points per thread (R17-proven mix)
#define XCHUNK (256 * XPT)        // 512
#define NXC    (NPTS / XCHUNK)    // 8
#define YCHUNK 128                // y-points per block (64 pairs)
#define NPAIR  (YCHUNK / 2)       // 64
#define NYC    (NPTS / YCHUNK)    // 32
#define BIGF   1e30f

typedef float v2f __attribute__((ext_vector_type(2)));

// Kernel 1: partial mins with packed-f32 math.
// grid = (NXC, NYC, 2*NBATCH) = (8,32,8) = 2048 blocks -> 8 blocks/CU,
// 8 waves/SIMD, SAME per-pair instruction mix as R17 (2.0 VALU + 0.5 ds_read).
__global__ __launch_bounds__(256)
void chamfer_min_kernel(const float* __restrict__ preds,
                        const float* __restrict__ gts,
                        const int* __restrict__ mask,
                        float* __restrict__ partial,
                        float* __restrict__ out) {
    const int zc  = blockIdx.z;
    const int dir = zc >> 2;
    const int b   = zc & 3;
    const int tid = threadIdx.x;

    // zero the output scalar exactly once (kernel2 accumulates after boundary)
    if ((zc | blockIdx.x | blockIdx.y | tid) == 0) out[0] = 0.0f;

    const float* X = (dir == 0 ? preds : gts) + (size_t)b * NPTS * 3;
    const float* Y = (dir == 0 ? gts : preds) + (size_t)b * NPTS * 3;

    __shared__ float4 sp[2 * NPAIR];   // 2 KB
    const int cbase = blockIdx.y * YCHUNK;
    if (tid < NPAIR) {
        const int ja = cbase + 2 * tid;
        const int jb = ja + 1;
        const float xa = Y[ja * 3 + 0], ya = Y[ja * 3 + 1], za = Y[ja * 3 + 2];
        const float xb = Y[jb * 3 + 0], yb = Y[jb * 3 + 1], zb = Y[jb * 3 + 2];
        float ra = xa * xa + ya * ya + za * za;
        float rb = xb * xb + yb * yb + zb * zb;
        if (dir == 0) {
            if (mask[b * NPTS + ja] == 0) ra = BIGF;
            if (mask[b * NPTS + jb] == 0) rb = BIGF;
        }
        sp[2 * tid + 0] = make_float4(xa, xb, ya, yb);
        sp[2 * tid + 1] = make_float4(za, zb, ra, rb);
    }

    // load XPT=2 x-points; hoist packed splats of (-2x)
    v2f A0[XPT], A1[XPT], A2[XPT];
    float rx[XPT], m[XPT];
    const int xbase = blockIdx.x * XCHUNK + tid;
    #pragma unroll
    for (int i = 0; i < XPT; ++i) {
        const int x = xbase + i * 256;
        const float v0 = X[x * 3 + 0], v1 = X[x * 3 + 1], v2 = X[x * 3 + 2];
        rx[i] = v0 * v0 + v1 * v1 + v2 * v2;
        const float s0 = -2.0f * v0, s1 = -2.0f * v1, s2 = -2.0f * v2;
        A0[i] = (v2f){s0, s0}; A1[i] = (v2f){s1, s1}; A2[i] = (v2f){s2, s2};
        m[i] = BIGF;
    }
    __syncthreads();

    #pragma unroll 4
    for (int j = 0; j < NPAIR; ++j) {
        const float4 E0 = sp[2 * j + 0];   // (x_a,x_b,y_a,y_b) broadcast
        const float4 E1 = sp[2 * j + 1];   // (z_a,z_b,ra,rb)
        const v2f X2 = (v2f){E0.x, E0.y};
        const v2f Y2 = (v2f){E0.z, E0.w};
        const v2f Z2 = (v2f){E1.x, E1.y};
        const v2f R2 = (v2f){E1.z, E1.w};
        #pragma unroll
        for (int i = 0; i < XPT; ++i) {
            // t = R2 + A2*Z2 + A1*Y2 + A0*X2  (3 x v_pk_fma_f32)
            v2f t = __builtin_elementwise_fma(A2[i], Z2, R2);
            t = __builtin_elementwise_fma(A1[i], Y2, t);
            t = __builtin_elementwise_fma(A0[i], X2, t);
            m[i] = fminf(fminf(m[i], t.x), t.y);   // -> v_min3_f32
        }
    }

    float* prow = partial + ((size_t)zc * NYC + blockIdx.y) * NPTS + xbase;
    #pragma unroll
    for (int i = 0; i < XPT; ++i)
        prow[i * 256] = rx[i] + m[i];
}

// Kernel 2: per point min over NYC=32 rows. 2 threads per float4-column
// (16 rows each, shfl_xor combine) -> 64 blocks of 256.
__global__ __launch_bounds__(256)
void chamfer_reduce_kernel(const float* __restrict__ partial,
                           const int* __restrict__ mask,
                           float* __restrict__ out) {
    const int gid = blockIdx.x * blockDim.x + threadIdx.x;
    const int h   = gid & 1;            // row-half
    const int c   = gid >> 1;           // float4-column id
    const int p4  = c * 4;              // first of 4 consecutive points
    const int dir = p4 >> 14;
    const int b   = (p4 >> 12) & 3;
    const int x   = p4 & 4095;
    const int zc  = dir * NBATCH + b;

    const float4* base = (const float4*)(partial + (size_t)zc * NYC * NPTS + x)
                       + (size_t)(h * 16) * (NPTS / 4);
    float4 m4 = base[0];
    #pragma unroll
    for (int r = 1; r < 16; ++r) {
        const float4 v = base[(size_t)r * (NPTS / 4)];
        m4.x = fminf(m4.x, v.x); m4.y = fminf(m4.y, v.y);
        m4.z = fminf(m4.z, v.z); m4.w = fminf(m4.w, v.w);
    }
    // combine halves (lanes 2i, 2i+1)
    m4.x = fminf(m4.x, __shfl_xor(m4.x, 1, 64));
    m4.y = fminf(m4.y, __shfl_xor(m4.y, 1, 64));
    m4.z = fminf(m4.z, __shfl_xor(m4.z, 1, 64));
    m4.w = fminf(m4.w, __shfl_xor(m4.w, 1, 64));

    float acc = 0.0f;
    if (h == 0) {
        if (dir == 1) {
            const int4 mk = *(const int4*)(mask + b * NPTS + x);
            acc = (mk.x ? m4.x : 0.0f) + (mk.y ? m4.y : 0.0f)
                + (mk.z ? m4.z : 0.0f) + (mk.w ? m4.w : 0.0f);
        } else {
            acc = m4.x + m4.y + m4.z + m4.w;
        }
    }

    #pragma unroll
    for (int off = 32; off > 0; off >>= 1)
        acc += __shfl_down(acc, off, 64);

    __shared__ float wsum[4];
    if ((threadIdx.x & 63) == 0) wsum[threadIdx.x >> 6] = acc;
    __syncthreads();
    if (threadIdx.x == 0)
        atomicAdd(out, wsum[0] + wsum[1] + wsum[2] + wsum[3]);
}

extern "C" void kernel_launch(void* const* d_in, const int* in_sizes, int n_in,
                              void* d_out, int out_size, void* d_ws, size_t ws_size,
                              hipStream_t stream) {
    const float* preds = (const float*)d_in[0];  // [B, Npred, 3]
    const float* gts   = (const float*)d_in[1];  // [B, Ngt, 3]
    const int*   mask  = (const int*)d_in[2];    // [B, Ngt]
    float* out = (float*)d_out;

    float* partial = (float*)d_ws;  // [8][NYC][NPTS] = 4 MB

    dim3 grid(NXC, NYC, 2 * NBATCH);
    chamfer_min_kernel<<<grid, 256, 0, stream>>>(preds, gts, mask, partial, out);

    chamfer_reduce_kernel<<<2 * (2 * NBATCH * NPTS / 4) / 256, 256, 0, stream>>>(
        partial, mask, out);
}

// Round 20
// 19.703 us; speedup vs baseline: 1.2455x; 1.0011x over previous
//
#include <hip/hip_runtime.h>

#define NBATCH 4
#define NPTS   4096
#define XPT    2                  // x-points per thread (R17-proven mix)
#define XCHUNK (256 * XPT)        // 512
#define NXC    (NPTS / XCHUNK)    // 8
#define YCHUNK 256                // y-points per block (128 pairs)
#define NPAIR  (YCHUNK / 2)       // 128
#define NYC    (NPTS / YCHUNK)    // 16
#define BIGF   1e30f

typedef float v2f __attribute__((ext_vector_type(2)));

// Kernel 1: partial mins with packed-f32 math. R17 geometry:
// grid = (NXC, NYC, 2*NBATCH) = (8,16,8) = 1024 blocks (4/CU, 4 waves/SIMD).
// Y-chunk staged via COALESCED float4 loads into raw LDS (192 threads x 1
// load = 768 floats), mask via int4 (64 threads), then repacked to the
// pair layout E0=(x_a,x_b,y_a,y_b), E1=(z_a,z_b,ry_a,ry_b).
// Inner step per x: 3 v_pk_fma_f32 + 1 v_min3_f32 for TWO y (2 instr/pair).
__global__ __launch_bounds__(256)
void chamfer_min_kernel(const float* __restrict__ preds,
                        const float* __restrict__ gts,
                        const int* __restrict__ mask,
                        float* __restrict__ partial,
                        float* __restrict__ out) {
    const int zc  = blockIdx.z;
    const int dir = zc >> 2;
    const int b   = zc & 3;
    const int tid = threadIdx.x;

    // zero the output scalar exactly once (kernel2 accumulates after boundary)
    if ((zc | blockIdx.x | blockIdx.y | tid) == 0) out[0] = 0.0f;

    const float* X = (dir == 0 ? preds : gts) + (size_t)b * NPTS * 3;
    const float* Y = (dir == 0 ? gts : preds) + (size_t)b * NPTS * 3;

    __shared__ float  raw[YCHUNK * 3];   // 3 KB
    __shared__ int    smask[YCHUNK];     // 1 KB
    __shared__ float4 sp[2 * NPAIR];     // 4 KB

    const int cbase = blockIdx.y * YCHUNK;
    // coalesced staging: Y rows (cbase*12 bytes offset, 3072B-aligned)
    if (tid < (YCHUNK * 3) / 4)
        ((float4*)raw)[tid] = ((const float4*)(Y + (size_t)cbase * 3))[tid];
    if (dir == 0 && tid < YCHUNK / 4)
        ((int4*)smask)[tid] = ((const int4*)(mask + b * NPTS + cbase))[tid];

    // x-point prologue (independent of staging; scheduler overlaps)
    v2f A0[XPT], A1[XPT], A2[XPT];
    float rx[XPT], m[XPT];
    const int xbase = blockIdx.x * XCHUNK + tid;
    #pragma unroll
    for (int i = 0; i < XPT; ++i) {
        const int x = xbase + i * 256;
        const float v0 = X[x * 3 + 0], v1 = X[x * 3 + 1], v2 = X[x * 3 + 2];
        rx[i] = v0 * v0 + v1 * v1 + v2 * v2;
        const float s0 = -2.0f * v0, s1 = -2.0f * v1, s2 = -2.0f * v2;
        A0[i] = (v2f){s0, s0}; A1[i] = (v2f){s1, s1}; A2[i] = (v2f){s2, s2};
        m[i] = BIGF;
    }
    __syncthreads();

    // repack pair t from LDS (6 ds_reads, worst 4-way conflict)
    if (tid < NPAIR) {
        const float xa = raw[6 * tid + 0], ya = raw[6 * tid + 1], za = raw[6 * tid + 2];
        const float xb = raw[6 * tid + 3], yb = raw[6 * tid + 4], zb = raw[6 * tid + 5];
        float ra = xa * xa + ya * ya + za * za;
        float rb = xb * xb + yb * yb + zb * zb;
        if (dir == 0) {
            if (smask[2 * tid + 0] == 0) ra = BIGF;
            if (smask[2 * tid + 1] == 0) rb = BIGF;
        }
        sp[2 * tid + 0] = make_float4(xa, xb, ya, yb);
        sp[2 * tid + 1] = make_float4(za, zb, ra, rb);
    }
    __syncthreads();

    #pragma unroll 4
    for (int j = 0; j < NPAIR; ++j) {
        const float4 E0 = sp[2 * j + 0];   // (x_a,x_b,y_a,y_b) broadcast
        const float4 E1 = sp[2 * j + 1];   // (z_a,z_b,ra,rb)
        const v2f X2 = (v2f){E0.x, E0.y};
        const v2f Y2 = (v2f){E0.z, E0.w};
        const v2f Z2 = (v2f){E1.x, E1.y};
        const v2f R2 = (v2f){E1.z, E1.w};
        #pragma unroll
        for (int i = 0; i < XPT; ++i) {
            // t = R2 + A2*Z2 + A1*Y2 + A0*X2  (3 x v_pk_fma_f32)
            v2f t = __builtin_elementwise_fma(A2[i], Z2, R2);
            t = __builtin_elementwise_fma(A1[i], Y2, t);
            t = __builtin_elementwise_fma(A0[i], X2, t);
            m[i] = fminf(fminf(m[i], t.x), t.y);   // -> v_min3_f32
        }
    }

    float* prow = partial + ((size_t)zc * NYC + blockIdx.y) * NPTS + xbase;
    #pragma unroll
    for (int i = 0; i < XPT; ++i)
        prow[i * 256] = rx[i] + m[i];
}

// Kernel 2: per point min over NYC=16 rows. 2 threads per float4-column
// (8 rows each, shfl_xor combine) -> 64 blocks of 256.
__global__ __launch_bounds__(256)
void chamfer_reduce_kernel(const float* __restrict__ partial,
                           const int* __restrict__ mask,
                           float* __restrict__ out) {
    const int gid = blockIdx.x * blockDim.x + threadIdx.x;
    const int h   = gid & 1;            // row-half
    const int c   = gid >> 1;           // float4-column id
    const int p4  = c * 4;              // first of 4 consecutive points
    const int dir = p4 >> 14;
    const int b   = (p4 >> 12) & 3;
    const int x   = p4 & 4095;
    const int zc  = dir * NBATCH + b;

    const float4* base = (const float4*)(partial + (size_t)zc * NYC * NPTS + x)
                       + (size_t)(h * 8) * (NPTS / 4);
    float4 m4 = base[0];
    #pragma unroll
    for (int r = 1; r < 8; ++r) {
        const float4 v = base[(size_t)r * (NPTS / 4)];
        m4.x = fminf(m4.x, v.x); m4.y = fminf(m4.y, v.y);
        m4.z = fminf(m4.z, v.z); m4.w = fminf(m4.w, v.w);
    }
    // combine halves (lanes 2i, 2i+1)
    m4.x = fminf(m4.x, __shfl_xor(m4.x, 1, 64));
    m4.y = fminf(m4.y, __shfl_xor(m4.y, 1, 64));
    m4.z = fminf(m4.z, __shfl_xor(m4.z, 1, 64));
    m4.w = fminf(m4.w, __shfl_xor(m4.w, 1, 64));

    float acc = 0.0f;
    if (h == 0) {
        if (dir == 1) {
            const int4 mk = *(const int4*)(mask + b * NPTS + x);
            acc = (mk.x ? m4.x : 0.0f) + (mk.y ? m4.y : 0.0f)
                + (mk.z ? m4.z : 0.0f) + (mk.w ? m4.w : 0.0f);
        } else {
            acc = m4.x + m4.y + m4.z + m4.w;
        }
    }

    #pragma unroll
    for (int off = 32; off > 0; off >>= 1)
        acc += __shfl_down(acc, off, 64);

    __shared__ float wsum[4];
    if ((threadIdx.x & 63) == 0) wsum[threadIdx.x >> 6] = acc;
    __syncthreads();
    if (threadIdx.x == 0)
        atomicAdd(out, wsum[0] + wsum[1] + wsum[2] + wsum[3]);
}

extern "C" void kernel_launch(void* const* d_in, const int* in_sizes, int n_in,
                              void* d_out, int out_size, void* d_ws, size_t ws_size,
                              hipStream_t stream) {
    const float* preds = (const float*)d_in[0];  // [B, Npred, 3]
    const float* gts   = (const float*)d_in[1];  // [B, Ngt, 3]
    const int*   mask  = (const int*)d_in[2];    // [B, Ngt]
    float* out = (float*)d_out;

    float* partial = (float*)d_ws;  // [8][NYC][NPTS] = 2 MB

    dim3 grid(NXC, NYC, 2 * NBATCH);
    chamfer_min_kernel<<<grid, 256, 0, stream>>>(preds, gts, mask, partial, out);

    chamfer_reduce_kernel<<<2 * (2 * NBATCH * NPTS / 4) / 256, 256, 0, stream>>>(
        partial, mask, out);
}

// Round 21
// 19.290 us; speedup vs baseline: 1.2722x; 1.0214x over previous
//
#include <hip/hip_runtime.h>

#define NBATCH 4
#define NPTS   4096
#define XPT    2                  // x-points per thread (proven optimum, R17-R19)
#define XCHUNK (256 * XPT)        // 512
#define NXC    (NPTS / XCHUNK)    // 8
#define YCHUNK 256                // y-points per block (128 pairs)
#define NPAIR  (YCHUNK / 2)       // 128
#define NYC    (NPTS / YCHUNK)    // 16
#define BIGF   1e30f

typedef float v2f __attribute__((ext_vector_type(2)));

// Kernel 1: partial mins with packed-f32 math. R17 configuration (best: 19.22us).
// grid = (NXC, NYC, 2*NBATCH) = (8,16,8) = 1024 blocks (4/CU, 4 waves/SIMD).
// LDS pair layout per y-pair j: E0=(x_a,x_b,y_a,y_b), E1=(z_a,z_b,ry_a,ry_b)
// -> inner step per x: 3 v_pk_fma_f32 + 1 v_min3_f32 for TWO y (2 instr/pair,
// the algorithmic minimum for the rx+min(ry-2x.y) expansion).
__global__ __launch_bounds__(256)
void chamfer_min_kernel(const float* __restrict__ preds,
                        const float* __restrict__ gts,
                        const int* __restrict__ mask,
                        float* __restrict__ partial,
                        float* __restrict__ out) {
    const int zc  = blockIdx.z;
    const int dir = zc >> 2;
    const int b   = zc & 3;
    const int tid = threadIdx.x;

    // zero the output scalar exactly once (kernel2 accumulates after boundary)
    if ((zc | blockIdx.x | blockIdx.y | tid) == 0) out[0] = 0.0f;

    const float* X = (dir == 0 ? preds : gts) + (size_t)b * NPTS * 3;
    const float* Y = (dir == 0 ? gts : preds) + (size_t)b * NPTS * 3;

    __shared__ float4 sp[2 * NPAIR];   // 4 KB
    const int cbase = blockIdx.y * YCHUNK;
    if (tid < NPAIR) {
        const int ja = cbase + 2 * tid;
        const int jb = ja + 1;
        const float xa = Y[ja * 3 + 0], ya = Y[ja * 3 + 1], za = Y[ja * 3 + 2];
        const float xb = Y[jb * 3 + 0], yb = Y[jb * 3 + 1], zb = Y[jb * 3 + 2];
        float ra = xa * xa + ya * ya + za * za;
        float rb = xb * xb + yb * yb + zb * zb;
        if (dir == 0) {
            if (mask[b * NPTS + ja] == 0) ra = BIGF;
            if (mask[b * NPTS + jb] == 0) rb = BIGF;
        }
        sp[2 * tid + 0] = make_float4(xa, xb, ya, yb);
        sp[2 * tid + 1] = make_float4(za, zb, ra, rb);
    }

    // load XPT=2 x-points; hoist packed splats of (-2x) out of the y-loop
    v2f A0[XPT], A1[XPT], A2[XPT];
    float rx[XPT], m[XPT];
    const int xbase = blockIdx.x * XCHUNK + tid;
    #pragma unroll
    for (int i = 0; i < XPT; ++i) {
        const int x = xbase + i * 256;
        const float v0 = X[x * 3 + 0], v1 = X[x * 3 + 1], v2 = X[x * 3 + 2];
        rx[i] = v0 * v0 + v1 * v1 + v2 * v2;
        const float s0 = -2.0f * v0, s1 = -2.0f * v1, s2 = -2.0f * v2;
        A0[i] = (v2f){s0, s0}; A1[i] = (v2f){s1, s1}; A2[i] = (v2f){s2, s2};
        m[i] = BIGF;
    }
    __syncthreads();

    #pragma unroll 4
    for (int j = 0; j < NPAIR; ++j) {
        const float4 E0 = sp[2 * j + 0];   // (x_a,x_b,y_a,y_b) broadcast
        const float4 E1 = sp[2 * j + 1];   // (z_a,z_b,ra,rb)
        const v2f X2 = (v2f){E0.x, E0.y};
        const v2f Y2 = (v2f){E0.z, E0.w};
        const v2f Z2 = (v2f){E1.x, E1.y};
        const v2f R2 = (v2f){E1.z, E1.w};
        #pragma unroll
        for (int i = 0; i < XPT; ++i) {
            // t = R2 + A2*Z2 + A1*Y2 + A0*X2  (3 x v_pk_fma_f32)
            v2f t = __builtin_elementwise_fma(A2[i], Z2, R2);
            t = __builtin_elementwise_fma(A1[i], Y2, t);
            t = __builtin_elementwise_fma(A0[i], X2, t);
            m[i] = fminf(fminf(m[i], t.x), t.y);   // -> v_min3_f32
        }
    }

    float* prow = partial + ((size_t)zc * NYC + blockIdx.y) * NPTS + xbase;
    #pragma unroll
    for (int i = 0; i < XPT; ++i)
        prow[i * 256] = rx[i] + m[i];
}

// Kernel 2: per point min over NYC=16 rows. 2 threads per float4-column
// (8 rows each, shfl_xor combine) -> 64 blocks of 256.
__global__ __launch_bounds__(256)
void chamfer_reduce_kernel(const float* __restrict__ partial,
                           const int* __restrict__ mask,
                           float* __restrict__ out) {
    const int gid = blockIdx.x * blockDim.x + threadIdx.x;
    const int h   = gid & 1;            // row-half
    const int c   = gid >> 1;           // float4-column id
    const int p4  = c * 4;              // first of 4 consecutive points
    const int dir = p4 >> 14;
    const int b   = (p4 >> 12) & 3;
    const int x   = p4 & 4095;
    const int zc  = dir * NBATCH + b;

    const float4* base = (const float4*)(partial + (size_t)zc * NYC * NPTS + x)
                       + (size_t)(h * 8) * (NPTS / 4);
    float4 m4 = base[0];
    #pragma unroll
    for (int r = 1; r < 8; ++r) {
        const float4 v = base[(size_t)r * (NPTS / 4)];
        m4.x = fminf(m4.x, v.x); m4.y = fminf(m4.y, v.y);
        m4.z = fminf(m4.z, v.z); m4.w = fminf(m4.w, v.w);
    }
    // combine halves (lanes 2i, 2i+1)
    m4.x = fminf(m4.x, __shfl_xor(m4.x, 1, 64));
    m4.y = fminf(m4.y, __shfl_xor(m4.y, 1, 64));
    m4.z = fminf(m4.z, __shfl_xor(m4.z, 1, 64));
    m4.w = fminf(m4.w, __shfl_xor(m4.w, 1, 64));

    float acc = 0.0f;
    if (h == 0) {
        if (dir == 1) {
            const int4 mk = *(const int4*)(mask + b * NPTS + x);
            acc = (mk.x ? m4.x : 0.0f) + (mk.y ? m4.y : 0.0f)
                + (mk.z ? m4.z : 0.0f) + (mk.w ? m4.w : 0.0f);
        } else {
            acc = m4.x + m4.y + m4.z + m4.w;
        }
    }

    #pragma unroll
    for (int off = 32; off > 0; off >>= 1)
        acc += __shfl_down(acc, off, 64);

    __shared__ float wsum[4];
    if ((threadIdx.x & 63) == 0) wsum[threadIdx.x >> 6] = acc;
    __syncthreads();
    if (threadIdx.x == 0)
        atomicAdd(out, wsum[0] + wsum[1] + wsum[2] + wsum[3]);
}

extern "C" void kernel_launch(void* const* d_in, const int* in_sizes, int n_in,
                              void* d_out, int out_size, void* d_ws, size_t ws_size,
                              hipStream_t stream) {
    const float* preds = (const float*)d_in[0];  // [B, Npred, 3]
    const float* gts   = (const float*)d_in[1];  // [B, Ngt, 3]
    const int*   mask  = (const int*)d_in[2];    // [B, Ngt]
    float* out = (float*)d_out;

    float* partial = (float*)d_ws;  // [8][NYC][NPTS] = 2 MB

    dim3 grid(NXC, NYC, 2 * NBATCH);
    chamfer_min_kernel<<<grid, 256, 0, stream>>>(preds, gts, mask, partial, out);

    chamfer_reduce_kernel<<<2 * (2 * NBATCH * NPTS / 4) / 256, 256, 0, stream>>>(
        partial, mask, out);
}